// Round 2
// baseline (44.964 us; speedup 1.0000x reference)
//
#include <hip/hip_runtime.h>
#include <math.h>

#define NY 74
#define NX 74
#define HH 512
#define WW 512
#define CC 3
#define BB 16

struct F3 { float a, b, c; };

__global__ __launch_bounds__(128) void stb_kernel(
    const float* __restrict__ fmap, const float* __restrict__ theta,
    float* __restrict__ out, float* __restrict__ delta_out)
{
    // one block per (b,h) image row
    const int row = blockIdx.x;        // b*HH + h
    const int h = row & (HH - 1);
    const int b = row >> 9;

    // 1/sx where sx = 512/71 (f32). 71/512 is EXACTLY representable (denom = 2^9),
    // and cubic B-splines are C2-continuous, so any floor-boundary difference vs
    // the reference's divide changes delta only at fp-rounding level.
    const float inv_s = 71.0f / 512.0f;

    __shared__ float2 S[NX];

    const int t = threadIdx.x;
    if (t < NX) {
        // row-constant Bv basis
        float qy = (float)h * inv_s;
        float pyf = floorf(qy);
        float v = qy - pyf;
        int py = (int)pyf;
        float v2 = v * v, v3 = v2 * v;
        float Bv0 = (-v3 + 3.f * v2 - 3.f * v + 1.f) * (1.f / 6.f);
        float Bv1 = (3.f * v3 - 6.f * v2 + 4.f) * (1.f / 6.f);
        float Bv2 = (-v3 * 3.f + 3.f * v2 + 3.f * v + 1.f) * (1.f / 6.f);
        float Bv3 = v3 * (1.f / 6.f);

        const float* thx = theta + (size_t)b * 2 * NY * NX; // theta[b,0]
        const float* thy = thx + NY * NX;                   // theta[b,1]
        int base = py * NX + t;
        float sxv = Bv0 * thx[base] + Bv1 * thx[base + NX] +
                    Bv2 * thx[base + 2 * NX] + Bv3 * thx[base + 3 * NX];
        float syv = Bv0 * thy[base] + Bv1 * thy[base + NX] +
                    Bv2 * thy[base + 2 * NX] + Bv3 * thy[base + 3 * NX];
        S[t] = make_float2(sxv, syv);
    }
    __syncthreads();

    const float* fb = fmap + (size_t)b * HH * WW * CC;
    const float yh = (float)h;
    const int w0 = t * 4;

    float outv[12];
    float dxv[4], dyv[4];

    #pragma unroll
    for (int k = 0; k < 4; ++k) {
        int w = w0 + k;
        float xw = (float)w;
        float qx = xw * inv_s;
        float pxf = floorf(qx);
        float u = qx - pxf;
        int px = (int)pxf;

        float u2 = u * u, u3 = u2 * u;
        float Bu0 = (-u3 + 3.f * u2 - 3.f * u + 1.f) * (1.f / 6.f);
        float Bu1 = (3.f * u3 - 6.f * u2 + 4.f) * (1.f / 6.f);
        float Bu2 = (-u3 * 3.f + 3.f * u2 + 3.f * u + 1.f) * (1.f / 6.f);
        float Bu3 = u3 * (1.f / 6.f);

        float2 s0 = S[px], s1 = S[px + 1], s2 = S[px + 2], s3 = S[px + 3];
        float dx = Bu0 * s0.x + Bu1 * s1.x + Bu2 * s2.x + Bu3 * s3.x;
        float dy = Bu0 * s0.y + Bu1 * s1.y + Bu2 * s2.y + Bu3 * s3.y;

        float xs = xw + dx;
        float ys = yh + dy;
        float x0f = floorf(xs);
        float y0f = floorf(ys);
        int x0 = (int)x0f;
        int y0 = (int)y0f;
        // reference clamp order: x1 from pre-clamp x0
        int x1 = min(max(x0 + 1, 0), WW - 1);
        int y1 = min(max(y0 + 1, 0), HH - 1);
        x0 = min(max(x0, 0), WW - 1);
        y0 = min(max(y0, 0), HH - 1);

        float wa = ((float)x1 - xs) * ((float)y1 - ys);
        float wb = ((float)x1 - xs) * (ys - (float)y0);
        float wc = (xs - (float)x0) * ((float)y1 - ys);
        float wd = (xs - (float)x0) * (ys - (float)y0);

        F3 Ia = *(const F3*)(fb + ((size_t)y0 * WW + x0) * CC);
        F3 Ib = *(const F3*)(fb + ((size_t)y1 * WW + x0) * CC);
        F3 Ic = *(const F3*)(fb + ((size_t)y0 * WW + x1) * CC);
        F3 Id = *(const F3*)(fb + ((size_t)y1 * WW + x1) * CC);

        outv[k * 3 + 0] = wa * Ia.a + wb * Ib.a + wc * Ic.a + wd * Id.a;
        outv[k * 3 + 1] = wa * Ia.b + wb * Ib.b + wc * Ic.b + wd * Id.b;
        outv[k * 3 + 2] = wa * Ia.c + wb * Ib.c + wc * Ic.c + wd * Id.c;

        dxv[k] = dx;
        dyv[k] = dy;
    }

    // vectorized stores: 4 pixels * 3ch = 48B (16B-aligned since pix0 % 4 == 0)
    const size_t pix0 = (size_t)row * WW + w0;
    float4* op = (float4*)(out + pix0 * CC);
    op[0] = make_float4(outv[0], outv[1], outv[2], outv[3]);
    op[1] = make_float4(outv[4], outv[5], outv[6], outv[7]);
    op[2] = make_float4(outv[8], outv[9], outv[10], outv[11]);

    const size_t total = (size_t)BB * HH * WW;
    *(float4*)(delta_out + pix0) = make_float4(dxv[0], dxv[1], dxv[2], dxv[3]);
    *(float4*)(delta_out + total + pix0) = make_float4(dyv[0], dyv[1], dyv[2], dyv[3]);
}

extern "C" void kernel_launch(void* const* d_in, const int* in_sizes, int n_in,
                              void* d_out, int out_size, void* d_ws, size_t ws_size,
                              hipStream_t stream) {
    const float* fmap  = (const float*)d_in[0];
    const float* theta = (const float*)d_in[1];
    float* out = (float*)d_out;
    float* delta = out + (size_t)BB * HH * WW * CC;

    dim3 grid(BB * HH), block(128);
    stb_kernel<<<grid, block, 0, stream>>>(fmap, theta, out, delta);
}

// Round 3
// 37.656 us; speedup vs baseline: 1.1941x; 1.1941x over previous
//
#include <hip/hip_runtime.h>
#include <math.h>

#define NY 74
#define NX 74
#define HH 512
#define WW 512
#define CC 3
#define BB 16

struct F3 { float a, b, c; };

__global__ __launch_bounds__(256) void stb_kernel(
    const float* __restrict__ fmap, const float* __restrict__ theta,
    float* __restrict__ out, float* __restrict__ delta_out)
{
    // block = half image row (256 pixels); 1 thread = 1 pixel
    const int blk = blockIdx.x;          // 0 .. B*H*2-1
    const int row = blk >> 1;            // b*H + h
    const int h = row & (HH - 1);
    const int b = row >> 9;
    const int w0 = (blk & 1) << 8;       // 0 or 256

    // 71/512 is exactly representable; replaces the reference's divide.
    const float inv_s = 71.0f / 512.0f;
    const float c6 = 1.0f / 6.0f;

    __shared__ float2 S[NX];

    const int t = threadIdx.x;
    if (t < NX) {
        // row-constant Bv basis (Horner)
        float qy = (float)h * inv_s;
        float v = qy - floorf(qy);
        int py = (int)floorf(qy);
        float Bv0 = (((-v + 3.f) * v - 3.f) * v + 1.f) * c6;
        float Bv1 = ((3.f * v - 6.f) * v * v + 4.f) * c6;
        float Bv2 = (((-3.f * v + 3.f) * v + 3.f) * v + 1.f) * c6;
        float Bv3 = (v * v * v) * c6;

        const float* thx = theta + b * 2 * NY * NX; // theta[b,0]
        const float* thy = thx + NY * NX;           // theta[b,1]
        int base = py * NX + t;
        float sxv = Bv0 * thx[base] + Bv1 * thx[base + NX] +
                    Bv2 * thx[base + 2 * NX] + Bv3 * thx[base + 3 * NX];
        float syv = Bv0 * thy[base] + Bv1 * thy[base + NX] +
                    Bv2 * thy[base + 2 * NX] + Bv3 * thy[base + 3 * NX];
        S[t] = make_float2(sxv, syv);
    }
    __syncthreads();

    const int w = w0 + t;
    const float xw = (float)w;
    const float yh = (float)h;

    float qx = xw * inv_s;
    float u = qx - floorf(qx);
    int px = (int)floorf(qx);
    float Bu0 = (((-u + 3.f) * u - 3.f) * u + 1.f) * c6;
    float Bu1 = ((3.f * u - 6.f) * u * u + 4.f) * c6;
    float Bu2 = (((-3.f * u + 3.f) * u + 3.f) * u + 1.f) * c6;
    float Bu3 = (u * u * u) * c6;

    float2 s0 = S[px], s1 = S[px + 1], s2 = S[px + 2], s3 = S[px + 3];
    float dx = Bu0 * s0.x + Bu1 * s1.x + Bu2 * s2.x + Bu3 * s3.x;
    float dy = Bu0 * s0.y + Bu1 * s1.y + Bu2 * s2.y + Bu3 * s3.y;

    float xs = xw + dx;
    float ys = yh + dy;
    int x0 = (int)floorf(xs);
    int y0 = (int)floorf(ys);
    // reference clamp order: x1 from pre-clamp x0
    int x1 = min(max(x0 + 1, 0), WW - 1);
    int y1 = min(max(y0 + 1, 0), HH - 1);
    x0 = min(max(x0, 0), WW - 1);
    y0 = min(max(y0, 0), HH - 1);

    float wa = ((float)x1 - xs) * ((float)y1 - ys);
    float wb = ((float)x1 - xs) * (ys - (float)y0);
    float wc = (xs - (float)x0) * ((float)y1 - ys);
    float wd = (xs - (float)x0) * (ys - (float)y0);

    const float* fb = fmap + b * (HH * WW * CC);
    F3 Ia = *(const F3*)(fb + ((y0 << 9) + x0) * 3);
    F3 Ib = *(const F3*)(fb + ((y1 << 9) + x0) * 3);
    F3 Ic = *(const F3*)(fb + ((y0 << 9) + x1) * 3);
    F3 Id = *(const F3*)(fb + ((y1 << 9) + x1) * 3);

    const int pix = (row << 9) + w;
    float* op = out + pix * 3;
    op[0] = wa * Ia.a + wb * Ib.a + wc * Ic.a + wd * Id.a;
    op[1] = wa * Ia.b + wb * Ib.b + wc * Ic.b + wd * Id.b;
    op[2] = wa * Ia.c + wb * Ib.c + wc * Ic.c + wd * Id.c;

    const int total = BB * HH * WW;
    delta_out[pix] = dx;
    delta_out[total + pix] = dy;
}

extern "C" void kernel_launch(void* const* d_in, const int* in_sizes, int n_in,
                              void* d_out, int out_size, void* d_ws, size_t ws_size,
                              hipStream_t stream) {
    const float* fmap  = (const float*)d_in[0];
    const float* theta = (const float*)d_in[1];
    float* out = (float*)d_out;
    float* delta = out + (size_t)BB * HH * WW * CC;

    dim3 grid(BB * HH * 2), block(256);
    stb_kernel<<<grid, block, 0, stream>>>(fmap, theta, out, delta);
}

// Round 4
// 37.374 us; speedup vs baseline: 1.2031x; 1.0075x over previous
//
#include <hip/hip_runtime.h>
#include <math.h>

#define NY 74
#define NX 74
#define HH 512
#define WW 512
#define CC 3
#define BB 16

struct F3 { float a, b, c; };

__global__ __launch_bounds__(256) void stb_kernel(
    const float* __restrict__ fmap, const float* __restrict__ theta,
    float* __restrict__ out, float* __restrict__ delta_out)
{
    // block = half image row (256 pixels); 1 thread = 1 pixel
    const int blk = blockIdx.x;          // 0 .. B*H*2-1
    const int row = blk >> 1;            // b*H + h
    const int h = row & (HH - 1);
    const int b = row >> 9;
    const int w0 = (blk & 1) << 8;       // 0 or 256

    // 71/512 is exactly representable; replaces the reference's divide.
    const float inv_s = 71.0f / 512.0f;
    const float c6 = 1.0f / 6.0f;

    __shared__ float2 S[NX];

    const int t = threadIdx.x;
    if (t < NX) {
        // row-constant Bv basis (Horner)
        float qy = (float)h * inv_s;
        float v = qy - floorf(qy);
        int py = (int)floorf(qy);
        float Bv0 = (((-v + 3.f) * v - 3.f) * v + 1.f) * c6;
        float Bv1 = ((3.f * v - 6.f) * v * v + 4.f) * c6;
        float Bv2 = (((-3.f * v + 3.f) * v + 3.f) * v + 1.f) * c6;
        float Bv3 = (v * v * v) * c6;

        const float* thx = theta + b * 2 * NY * NX; // theta[b,0]
        const float* thy = thx + NY * NX;           // theta[b,1]
        int base = py * NX + t;
        float sxv = Bv0 * thx[base] + Bv1 * thx[base + NX] +
                    Bv2 * thx[base + 2 * NX] + Bv3 * thx[base + 3 * NX];
        float syv = Bv0 * thy[base] + Bv1 * thy[base + NX] +
                    Bv2 * thy[base + 2 * NX] + Bv3 * thy[base + 3 * NX];
        S[t] = make_float2(sxv, syv);
    }
    __syncthreads();

    const int w = w0 + t;
    const float xw = (float)w;
    const float yh = (float)h;

    float qx = xw * inv_s;
    float u = qx - floorf(qx);
    int px = (int)floorf(qx);
    float Bu0 = (((-u + 3.f) * u - 3.f) * u + 1.f) * c6;
    float Bu1 = ((3.f * u - 6.f) * u * u + 4.f) * c6;
    float Bu2 = (((-3.f * u + 3.f) * u + 3.f) * u + 1.f) * c6;
    float Bu3 = (u * u * u) * c6;

    float2 s0 = S[px], s1 = S[px + 1], s2 = S[px + 2], s3 = S[px + 3];
    float dx = Bu0 * s0.x + Bu1 * s1.x + Bu2 * s2.x + Bu3 * s3.x;
    float dy = Bu0 * s0.y + Bu1 * s1.y + Bu2 * s2.y + Bu3 * s3.y;

    float xs = xw + dx;
    float ys = yh + dy;
    int x0 = (int)floorf(xs);
    int y0 = (int)floorf(ys);
    // reference clamp order: x1 from pre-clamp x0
    int x1 = min(max(x0 + 1, 0), WW - 1);
    int y1 = min(max(y0 + 1, 0), HH - 1);
    x0 = min(max(x0, 0), WW - 1);
    y0 = min(max(y0, 0), HH - 1);

    float wa = ((float)x1 - xs) * ((float)y1 - ys);
    float wb = ((float)x1 - xs) * (ys - (float)y0);
    float wc = (xs - (float)x0) * ((float)y1 - ys);
    float wd = (xs - (float)x0) * (ys - (float)y0);

    const float* fb = fmap + b * (HH * WW * CC);
    F3 Ia = *(const F3*)(fb + ((y0 << 9) + x0) * 3);
    F3 Ib = *(const F3*)(fb + ((y1 << 9) + x0) * 3);
    F3 Ic = *(const F3*)(fb + ((y0 << 9) + x1) * 3);
    F3 Id = *(const F3*)(fb + ((y1 << 9) + x1) * 3);

    const int pix = (row << 9) + w;
    float* op = out + pix * 3;
    __builtin_nontemporal_store(wa * Ia.a + wb * Ib.a + wc * Ic.a + wd * Id.a, op + 0);
    __builtin_nontemporal_store(wa * Ia.b + wb * Ib.b + wc * Ic.b + wd * Id.b, op + 1);
    __builtin_nontemporal_store(wa * Ia.c + wb * Ib.c + wc * Ic.c + wd * Id.c, op + 2);

    const int total = BB * HH * WW;
    __builtin_nontemporal_store(dx, delta_out + pix);
    __builtin_nontemporal_store(dy, delta_out + total + pix);
}

extern "C" void kernel_launch(void* const* d_in, const int* in_sizes, int n_in,
                              void* d_out, int out_size, void* d_ws, size_t ws_size,
                              hipStream_t stream) {
    const float* fmap  = (const float*)d_in[0];
    const float* theta = (const float*)d_in[1];
    float* out = (float*)d_out;
    float* delta = out + (size_t)BB * HH * WW * CC;

    dim3 grid(BB * HH * 2), block(256);
    stb_kernel<<<grid, block, 0, stream>>>(fmap, theta, out, delta);
}

// Round 5
// 25.738 us; speedup vs baseline: 1.7470x; 1.4521x over previous
//
#include <hip/hip_runtime.h>
#include <math.h>

#define NY 74
#define NX 74
#define HH 512
#define WW 512
#define CC 3
#define BB 16

struct F3 { float a, b, c; };

__global__ __launch_bounds__(256) void stb_kernel(
    const float* __restrict__ fmap, const float* __restrict__ theta,
    float* __restrict__ out, float* __restrict__ delta_out)
{
    // XCD-aware bijective swizzle (nwg = 16384, % 8 == 0): XCD k gets a
    // contiguous band of logical blocks -> row-neighbor fmap reuse stays in
    // that XCD's private L2.
    const int nwg = BB * HH * 2;
    const int bid = blockIdx.x;
    const int blk = (bid & 7) * (nwg >> 3) + (bid >> 3);

    // block = half image row (256 pixels); 1 thread = 1 pixel
    const int row = blk >> 1;            // b*H + h
    const int h = row & (HH - 1);
    const int b = row >> 9;
    const int w0 = (blk & 1) << 8;       // 0 or 256

    // 71/512 is exactly representable; replaces the reference's divide.
    const float inv_s = 71.0f / 512.0f;
    const float c6 = 1.0f / 6.0f;

    __shared__ float2 S[NX];

    const int t = threadIdx.x;
    if (t < NX) {
        // row-constant Bv basis (Horner)
        float qy = (float)h * inv_s;
        float v = qy - floorf(qy);
        int py = (int)floorf(qy);
        float Bv0 = (((-v + 3.f) * v - 3.f) * v + 1.f) * c6;
        float Bv1 = ((3.f * v - 6.f) * v * v + 4.f) * c6;
        float Bv2 = (((-3.f * v + 3.f) * v + 3.f) * v + 1.f) * c6;
        float Bv3 = (v * v * v) * c6;

        const float* thx = theta + b * 2 * NY * NX; // theta[b,0]
        const float* thy = thx + NY * NX;           // theta[b,1]
        int base = py * NX + t;
        float sxv = Bv0 * thx[base] + Bv1 * thx[base + NX] +
                    Bv2 * thx[base + 2 * NX] + Bv3 * thx[base + 3 * NX];
        float syv = Bv0 * thy[base] + Bv1 * thy[base + NX] +
                    Bv2 * thy[base + 2 * NX] + Bv3 * thy[base + 3 * NX];
        S[t] = make_float2(sxv, syv);
    }
    __syncthreads();

    const int w = w0 + t;
    const float xw = (float)w;
    const float yh = (float)h;

    float qx = xw * inv_s;
    float u = qx - floorf(qx);
    int px = (int)floorf(qx);
    float Bu0 = (((-u + 3.f) * u - 3.f) * u + 1.f) * c6;
    float Bu1 = ((3.f * u - 6.f) * u * u + 4.f) * c6;
    float Bu2 = (((-3.f * u + 3.f) * u + 3.f) * u + 1.f) * c6;
    float Bu3 = (u * u * u) * c6;

    float2 s0 = S[px], s1 = S[px + 1], s2 = S[px + 2], s3 = S[px + 3];
    float dx = Bu0 * s0.x + Bu1 * s1.x + Bu2 * s2.x + Bu3 * s3.x;
    float dy = Bu0 * s0.y + Bu1 * s1.y + Bu2 * s2.y + Bu3 * s3.y;

    float xs = xw + dx;
    float ys = yh + dy;
    int x0 = (int)floorf(xs);
    int y0 = (int)floorf(ys);
    // reference clamp order: x1 from pre-clamp x0
    int x1 = min(max(x0 + 1, 0), WW - 1);
    int y1 = min(max(y0 + 1, 0), HH - 1);
    x0 = min(max(x0, 0), WW - 1);
    y0 = min(max(y0, 0), HH - 1);

    float wa = ((float)x1 - xs) * ((float)y1 - ys);
    float wb = ((float)x1 - xs) * (ys - (float)y0);
    float wc = (xs - (float)x0) * ((float)y1 - ys);
    float wd = (xs - (float)x0) * (ys - (float)y0);

    const float* fb = fmap + b * (HH * WW * CC);
    F3 Ia = *(const F3*)(fb + ((y0 << 9) + x0) * 3);
    F3 Ib = *(const F3*)(fb + ((y1 << 9) + x0) * 3);
    F3 Ic = *(const F3*)(fb + ((y0 << 9) + x1) * 3);
    F3 Id = *(const F3*)(fb + ((y1 << 9) + x1) * 3);

    const int pix = (row << 9) + w;
    float* op = out + pix * 3;
    __builtin_nontemporal_store(wa * Ia.a + wb * Ib.a + wc * Ic.a + wd * Id.a, op + 0);
    __builtin_nontemporal_store(wa * Ia.b + wb * Ib.b + wc * Ic.b + wd * Id.b, op + 1);
    __builtin_nontemporal_store(wa * Ia.c + wb * Ib.c + wc * Ic.c + wd * Id.c, op + 2);

    const int total = BB * HH * WW;
    __builtin_nontemporal_store(dx, delta_out + pix);
    __builtin_nontemporal_store(dy, delta_out + total + pix);
}

extern "C" void kernel_launch(void* const* d_in, const int* in_sizes, int n_in,
                              void* d_out, int out_size, void* d_ws, size_t ws_size,
                              hipStream_t stream) {
    const float* fmap  = (const float*)d_in[0];
    const float* theta = (const float*)d_in[1];
    float* out = (float*)d_out;
    float* delta = out + (size_t)BB * HH * WW * CC;

    dim3 grid(BB * HH * 2), block(256);
    stb_kernel<<<grid, block, 0, stream>>>(fmap, theta, out, delta);
}